// Round 7
// baseline (186.454 us; speedup 1.0000x reference)
//
#include <hip/hip_runtime.h>

typedef __attribute__((ext_vector_type(8))) short bf16x8;
typedef __attribute__((ext_vector_type(4))) float f32x4;
typedef __attribute__((ext_vector_type(4))) unsigned int u32x4;
typedef __attribute__((ext_vector_type(2))) unsigned int u32x2;
typedef __attribute__((ext_vector_type(4))) unsigned short u16x4;

#define H_ 16
#define B_ 2
#define T_ 2048
#define DH_ 64
#define MD_ 1024

static __device__ inline unsigned short f2bf(float f) {  // round-nearest-even
    union { float f; unsigned u; } x; x.f = f;
    unsigned r = (x.u + 0x7fffu + ((x.u >> 16) & 1u)) >> 16;
    return (unsigned short)r;
}
// pack two fp32 -> two bf16 (truncation), lo in low short. 1 v_perm_b32.
static __device__ inline unsigned int pack_bf2(float lo, float hi) {
    return __builtin_amdgcn_perm(__float_as_uint(hi), __float_as_uint(lo), 0x07060302u);
}
static __device__ inline float fexp2(float x) {
#if __has_builtin(__builtin_amdgcn_exp2f)
    return __builtin_amdgcn_exp2f(x);   // raw v_exp_f32
#else
    return exp2f(x);
#endif
}

// ---------------------------------------------------------------------------
// Kernel 1: prep (r4 config - measured best). blocks 0..1023: Wo fp32->bf16
// (RNE). 1024..2047: K fp32->bf16 (trunc). 2048..3071: V fp32 -> V^T bf16
// [hb][dh][T] via LDS. block 3072: zero merge flags (256 ints).
// ---------------------------------------------------------------------------
__global__ __launch_bounds__(256) void prep_k(const float* __restrict__ k,
                                              const float* __restrict__ v,
                                              const float* __restrict__ w,
                                              unsigned short* __restrict__ kb,
                                              unsigned short* __restrict__ vtb,
                                              unsigned short* __restrict__ wob,
                                              int* __restrict__ fl) {
    __shared__ __attribute__((aligned(16))) unsigned short vt64[64][64];
    const int blk = blockIdx.x;
    const int tid = threadIdx.x;
    if (blk < 1024) {
        int i = (blk * 256 + tid) * 4;
        f32x4 x = *(const f32x4*)(w + i);
        u16x4 y;
        y[0] = f2bf(x[0]); y[1] = f2bf(x[1]); y[2] = f2bf(x[2]); y[3] = f2bf(x[3]);
        *(u16x4*)(wob + i) = y;
    } else if (blk < 2048) {
        int j = blk - 1024;
        const int hb = j >> 5, s0 = (j & 31) * 64;
        const int row = tid >> 2, c = (tid & 3) * 16;
        const long off = (long)hb * (T_ * DH_) + (long)(s0 + row) * DH_ + c;
        const float* p = k + off;
        f32x4 a0 = *(const f32x4*)p;
        f32x4 a1 = *(const f32x4*)(p + 4);
        f32x4 a2 = *(const f32x4*)(p + 8);
        f32x4 a3 = *(const f32x4*)(p + 12);
        u32x4 w0, w1;
        w0[0] = pack_bf2(a0[0], a0[1]); w0[1] = pack_bf2(a0[2], a0[3]);
        w0[2] = pack_bf2(a1[0], a1[1]); w0[3] = pack_bf2(a1[2], a1[3]);
        w1[0] = pack_bf2(a2[0], a2[1]); w1[1] = pack_bf2(a2[2], a2[3]);
        w1[2] = pack_bf2(a3[0], a3[1]); w1[3] = pack_bf2(a3[2], a3[3]);
        *(u32x4*)(kb + off) = w0;
        *(u32x4*)(kb + off + 8) = w1;
    } else if (blk < 3072) {
        int j = blk - 2048;
        const int hb = j >> 5, s0 = (j & 31) * 64;
        const int vkp = tid & 31, vdg = tid >> 5;  // key-pair, dh-group
        const float* vp = v + (long)hb * (T_ * DH_) + (long)(s0 + 2 * vkp) * DH_ + vdg * 8;
        f32x4 va0 = *(const f32x4*)vp;
        f32x4 va1 = *(const f32x4*)(vp + 4);
        f32x4 vb0 = *(const f32x4*)(vp + DH_);
        f32x4 vb1 = *(const f32x4*)(vp + DH_ + 4);
#pragma unroll
        for (int jj = 0; jj < 4; jj++) {
            ((unsigned int*)&vt64[vdg * 8 + jj][0])[vkp]     = pack_bf2(va0[jj], vb0[jj]);
            ((unsigned int*)&vt64[vdg * 8 + 4 + jj][0])[vkp] = pack_bf2(va1[jj], vb1[jj]);
        }
        __syncthreads();
        const int dh = tid >> 2, kc = (tid & 3) * 16;
        u32x4 o0 = *(const u32x4*)&vt64[dh][kc];
        u32x4 o1 = *(const u32x4*)&vt64[dh][kc + 8];
        unsigned short* op = vtb + (long)hb * (DH_ * T_) + (long)dh * T_ + s0 + kc;
        *(u32x4*)op = o0;
        *(u32x4*)(op + 8) = o1;
    } else {
        for (int z = tid; z < 256; z += 256) fl[z] = 0;
    }
}

// ---------------------------------------------------------------------------
// Kernel 2: causal attention, BARRIER-FREE inner loop. K/V^T are L2-resident
// per XCD (1MB+1MB, pinned by XCD-affine schedule) -> each wave reads its
// MFMA fragments DIRECTLY from global (L1/L2), no LDS staging, no
// __syncthreads in the loop (Common-mistake #7: don't stage what L2-fits).
// LDS keeps only the per-wave P round-trip (in-wave DS ordering, no barrier).
// Waves are fully independent; each loops only over its own needed steps.
// 128-row q-tiles, wave = 32 q rows, swapped-operand MFMA (S^T=K.Q, O^T=V^T.P).
// Static CU-triple schedule + loser-merges protocol: unchanged from r4 (best).
// ---------------------------------------------------------------------------
#define SE2(t, lo, hi) ((unsigned)((t) | ((lo) << 4) | ((hi) << 10)))
__constant__ unsigned sched24[3][8] = {
    // slot 0 (largest chunk of each triple-type A..H)
    { SE2(15,0,16), SE2(7,0,16), SE2(14,0,15), SE2(14,15,30),
      SE2(13,0,14), SE2(13,14,28), SE2(12,13,26), SE2(11,12,24) },
    // slot 1
    { SE2(15,16,32), SE2(6,0,14), SE2(12,0,13), SE2(10,0,11),
      SE2(10,11,22), SE2(9,0,10), SE2(11,0,12), SE2(5,0,12) },
    // slot 2
    { SE2(0,0,2), SE2(1,0,4), SE2(2,0,6), SE2(3,0,8),
      SE2(8,0,9), SE2(9,10,20), SE2(8,9,18), SE2(4,0,10) },
};

__global__ __launch_bounds__(256, 3) void attn_k(const float* __restrict__ q,
                                                 const unsigned short* __restrict__ kb,
                                                 const unsigned short* __restrict__ vtb,
                                                 unsigned short* __restrict__ ctx,
                                                 float* __restrict__ Op,
                                                 float* __restrict__ lp,
                                                 int* __restrict__ fl) {
    const int i = blockIdx.x;
    const int xcd = i & 7, j = i >> 3;            // per-XCD stream of 96 blocks
    const int cu = j & 31, slot = j >> 5;         // 32 CUs x 3 slots
    const int type = cu >> 2, hbl = cu & 3;
    const unsigned e = sched24[slot][type];
    const int t  = (int)(e & 15u);                // tile index 0..15 (128 rows)
    const int lo = (int)((e >> 4) & 63u);
    const int hi = (int)(e >> 10);
    const int hb = xcd * 4 + hbl;                 // K/V of 4 hb stay in this XCD's L2
    const int h = hb >> 1, b = hb & 1;
    const int tid = threadIdx.x;
    const int wave = tid >> 6, lane = tid & 63;
    const int ln = lane & 15, quad = lane >> 4;

    __shared__ __attribute__((aligned(16))) unsigned short pl[4][32][72]; // per-wave P [q][key]
    __shared__ int sh_who;

    const long kbase = (long)hb * (T_ * DH_);
    const long vbase = (long)hb * (DH_ * T_);
    const int q0w = t * 128 + wave * 32;          // wave's first q row

    // Q fragments for both 16-row subtiles (RNE, 0.125*log2(e) folded)
    bf16x8 qf00, qf01, qf10, qf11;
    {
        const float qs = 0.18033688011112042f;
        const float* qp0 = q + kbase + (long)(q0w + ln) * DH_ + quad * 8;
        const float* qp1 = qp0 + 16 * DH_;
        f32x4 a0 = *(const f32x4*)qp0;
        f32x4 a1 = *(const f32x4*)(qp0 + 4);
        f32x4 b0 = *(const f32x4*)(qp0 + 32);
        f32x4 b1 = *(const f32x4*)(qp0 + 36);
        f32x4 c0 = *(const f32x4*)qp1;
        f32x4 c1 = *(const f32x4*)(qp1 + 4);
        f32x4 d0 = *(const f32x4*)(qp1 + 32);
        f32x4 d1 = *(const f32x4*)(qp1 + 36);
#pragma unroll
        for (int z = 0; z < 4; z++) {
            qf00[z]   = (short)f2bf(a0[z] * qs);
            qf00[4+z] = (short)f2bf(a1[z] * qs);
            qf01[z]   = (short)f2bf(b0[z] * qs);
            qf01[4+z] = (short)f2bf(b1[z] * qs);
            qf10[z]   = (short)f2bf(c0[z] * qs);
            qf10[4+z] = (short)f2bf(c1[z] * qs);
            qf11[z]   = (short)f2bf(d0[z] * qs);
            qf11[4+z] = (short)f2bf(d1[z] * qs);
        }
    }

    // O^T accumulators: oTu[dt][r] = O[q = q0w + u*16 + ln][dh = dt*16+quad*4+r]
    f32x4 oT0[4], oT1[4];
#pragma unroll
    for (int z = 0; z < 4; z++) { oT0[z] = f32x4{0.f,0.f,0.f,0.f}; oT1[z] = f32x4{0.f,0.f,0.f,0.f}; }
    float lsum0 = 0.f, lsum1 = 0.f;

    // this wave's own step range: no staging duty, no barriers
    const int hiw = min(hi, 2 * t + 1 + (wave >> 1));

#pragma unroll 1
    for (int step = lo; step < hiw; step++) {
        // K fragments direct from L2 (row stride 128B, 16B/lane, 16B-aligned)
        const unsigned short* kp0 = kb + kbase + (long)(step * 64 + ln) * DH_ + quad * 8;
        bf16x8 kfr[8];
#pragma unroll
        for (int nt = 0; nt < 4; nt++) {
            kfr[2*nt]     = *(const bf16x8*)(kp0 + nt * 16 * DH_);
            kfr[2*nt + 1] = *(const bf16x8*)(kp0 + nt * 16 * DH_ + 32);
        }
        // V^T fragments direct from L2 (issued now, consumed after softmax)
        const unsigned short* vp0 = vtb + vbase + (long)ln * T_ + step * 64 + quad * 8;
        bf16x8 vfr[8];
#pragma unroll
        for (int dt = 0; dt < 4; dt++) {
            vfr[2*dt]     = *(const bf16x8*)(vp0 + dt * 16 * T_);
            vfr[2*dt + 1] = *(const bf16x8*)(vp0 + dt * 16 * T_ + 32);
        }

        const bool dmask = (step * 64 + 63 > q0w);   // diagonal touches this wave
        const int dbase = step * 64 + quad * 4 - q0w - ln;

        // QK^T (shared K-frags across both q-subtiles), exp2, mask, pack -> pl
#pragma unroll
        for (int nt = 0; nt < 4; nt++) {
            f32x4 a0 = f32x4{0.f,0.f,0.f,0.f};
            a0 = __builtin_amdgcn_mfma_f32_16x16x32_bf16(kfr[2*nt], qf00, a0, 0, 0, 0);
            a0 = __builtin_amdgcn_mfma_f32_16x16x32_bf16(kfr[2*nt+1], qf01, a0, 0, 0, 0);
            f32x4 a1 = f32x4{0.f,0.f,0.f,0.f};
            a1 = __builtin_amdgcn_mfma_f32_16x16x32_bf16(kfr[2*nt], qf10, a1, 0, 0, 0);
            a1 = __builtin_amdgcn_mfma_f32_16x16x32_bf16(kfr[2*nt+1], qf11, a1, 0, 0, 0);
#pragma unroll
            for (int r = 0; r < 4; r++) { a0[r] = fexp2(a0[r]); a1[r] = fexp2(a1[r]); }
            if (dmask) {
#pragma unroll
                for (int r = 0; r < 4; r++) {
                    if (dbase + nt * 16 + r > 0)  a0[r] = 0.f;
                    if (dbase + nt * 16 + r > 16) a1[r] = 0.f;
                }
            }
            lsum0 += (a0[0] + a0[1]) + (a0[2] + a0[3]);
            lsum1 += (a1[0] + a1[1]) + (a1[2] + a1[3]);
            u32x2 w0, w1;
            w0[0] = pack_bf2(a0[0], a0[1]); w0[1] = pack_bf2(a0[2], a0[3]);
            w1[0] = pack_bf2(a1[0], a1[1]); w1[1] = pack_bf2(a1[2], a1[3]);
            *(u32x2*)&pl[wave][ln][nt * 16 + quad * 4]      = w0;
            *(u32x2*)&pl[wave][16 + ln][nt * 16 + quad * 4] = w1;
        }

        // per-wave buffer: in-wave DS ordering + lgkmcnt, no barrier needed
        bf16x8 pf00 = *(const bf16x8*)&pl[wave][ln][quad * 8];
        bf16x8 pf01 = *(const bf16x8*)&pl[wave][ln][32 + quad * 8];
        bf16x8 pf10 = *(const bf16x8*)&pl[wave][16 + ln][quad * 8];
        bf16x8 pf11 = *(const bf16x8*)&pl[wave][16 + ln][32 + quad * 8];

        // PV (shared V-frags): oTu[dt] += V^T . P_u
#pragma unroll
        for (int dt = 0; dt < 4; dt++) {
            oT0[dt] = __builtin_amdgcn_mfma_f32_16x16x32_bf16(vfr[2*dt], pf00, oT0[dt], 0, 0, 0);
            oT0[dt] = __builtin_amdgcn_mfma_f32_16x16x32_bf16(vfr[2*dt+1], pf01, oT0[dt], 0, 0, 0);
            oT1[dt] = __builtin_amdgcn_mfma_f32_16x16x32_bf16(vfr[2*dt], pf10, oT1[dt], 0, 0, 0);
            oT1[dt] = __builtin_amdgcn_mfma_f32_16x16x32_bf16(vfr[2*dt+1], pf11, oT1[dt], 0, 0, 0);
        }
    }

    // full row-sums (keys were split across quads)
    lsum0 += __shfl_xor(lsum0, 16); lsum0 += __shfl_xor(lsum0, 32);
    lsum1 += __shfl_xor(lsum1, 16); lsum1 += __shfl_xor(lsum1, 32);

    float rl0, rl1;
    if (t < 8) {
        rl0 = __builtin_amdgcn_rcpf(lsum0);
        rl1 = __builtin_amdgcn_rcpf(lsum1);
    } else {
        // split tile: publish partial in O^T slab [dh][q] (coalesced 64B per quad)
        const int c = (lo != 0) ? 1 : 0;
        const long slab = ((long)c * 32 + hb) * 8 + (t - 8);
        float* ob = Op + slab * 8192;
        const int ql0 = wave * 32 + ln, ql1 = ql0 + 16;
#pragma unroll
        for (int dt = 0; dt < 4; dt++)
#pragma unroll
            for (int r = 0; r < 4; r++) {
                const int dh = dt * 16 + quad * 4 + r;
                __hip_atomic_store(&ob[dh * 128 + ql0], oT0[dt][r],
                                   __ATOMIC_RELAXED, __HIP_MEMORY_SCOPE_AGENT);
                __hip_atomic_store(&ob[dh * 128 + ql1], oT1[dt][r],
                                   __ATOMIC_RELAXED, __HIP_MEMORY_SCOPE_AGENT);
            }
        if (quad == 0) {
            __hip_atomic_store(&lp[slab * 128 + ql0], lsum0,
                               __ATOMIC_RELAXED, __HIP_MEMORY_SCOPE_AGENT);
            __hip_atomic_store(&lp[slab * 128 + ql1], lsum1,
                               __ATOMIC_RELAXED, __HIP_MEMORY_SCOPE_AGENT);
        }
        __syncthreads();   // drains each wave's vmcnt -> partials visible at agent scope
        if (tid == 0)
            sh_who = __hip_atomic_fetch_add(&fl[hb * 8 + (t - 8)], 1,
                                            __ATOMIC_RELAXED, __HIP_MEMORY_SCOPE_AGENT);
        __syncthreads();
        if (sh_who != 1) return;   // first finisher exits; loser merges (block-uniform)
        const long slab2 = ((long)(c ^ 1) * 32 + hb) * 8 + (t - 8);
        const float* qb = Op + slab2 * 8192;
#pragma unroll
        for (int dt = 0; dt < 4; dt++)
#pragma unroll
            for (int r = 0; r < 4; r++) {
                const int dh = dt * 16 + quad * 4 + r;
                oT0[dt][r] += __hip_atomic_load(&qb[dh * 128 + ql0],
                                                __ATOMIC_RELAXED, __HIP_MEMORY_SCOPE_AGENT);
                oT1[dt][r] += __hip_atomic_load(&qb[dh * 128 + ql1],
                                                __ATOMIC_RELAXED, __HIP_MEMORY_SCOPE_AGENT);
            }
        lsum0 += __hip_atomic_load(&lp[slab2 * 128 + ql0],
                                   __ATOMIC_RELAXED, __HIP_MEMORY_SCOPE_AGENT);
        lsum1 += __hip_atomic_load(&lp[slab2 * 128 + ql1],
                                   __ATOMIC_RELAXED, __HIP_MEMORY_SCOPE_AGENT);
        rl0 = __builtin_amdgcn_rcpf(lsum0);
        rl1 = __builtin_amdgcn_rcpf(lsum1);
    }

    // epilogue: scale, pack bf16 (RNE), transpose via own-wave pl region
    // (in-wave DS ordering, no barrier), then coalesced 16B ctx stores.
#pragma unroll
    for (int dt = 0; dt < 4; dt++) {
        u16x4 y0, y1;
        y0[0] = f2bf(oT0[dt][0] * rl0); y0[1] = f2bf(oT0[dt][1] * rl0);
        y0[2] = f2bf(oT0[dt][2] * rl0); y0[3] = f2bf(oT0[dt][3] * rl0);
        y1[0] = f2bf(oT1[dt][0] * rl1); y1[1] = f2bf(oT1[dt][1] * rl1);
        y1[2] = f2bf(oT1[dt][2] * rl1); y1[3] = f2bf(oT1[dt][3] * rl1);
        *(u16x4*)&pl[wave][ln][dt * 16 + quad * 4]      = y0;
        *(u16x4*)&pl[wave][16 + ln][dt * 16 + quad * 4] = y1;
    }
    const int rr = lane >> 1, cc = (lane & 1) * 32;
    u32x4 z0 = *(const u32x4*)&pl[wave][rr][cc];
    u32x4 z1 = *(const u32x4*)&pl[wave][rr][cc + 8];
    u32x4 z2 = *(const u32x4*)&pl[wave][rr][cc + 16];
    u32x4 z3 = *(const u32x4*)&pl[wave][rr][cc + 24];
    unsigned short* cp = ctx + (long)(b * T_ + t * 128 + wave * 32 + rr) * MD_ + h * 64 + cc;
    *(u32x4*)cp = z0;
    *(u32x4*)(cp + 8) = z1;
    *(u32x4*)(cp + 16) = z2;
    *(u32x4*)(cp + 24) = z3;
}

// ---------------------------------------------------------------------------
// Kernel 3: projection GEMM. out[m][n] = ctx[m][:] . Wo[n][:] + bias[n]
// M=4096 N=1024 K=1024. BM=64 BN=64 BK=64 -> 1024 blocks (4/CU).
// XCD swizzle: each XCD owns 2 n-tiles (Wo slice 256 KB -> L2-resident).
// ---------------------------------------------------------------------------
__global__ __launch_bounds__(256, 4) void proj_k(const unsigned short* __restrict__ A,
                                                 const unsigned short* __restrict__ Bw,
                                                 const float* __restrict__ bias,
                                                 float* __restrict__ out) {
    const int i = blockIdx.x;
    const int n0 = ((i & 7) * 2 + ((i >> 3) & 1)) * 64;
    const int m0 = (i >> 4) * 64;
    const int tid = threadIdx.x;
    const int wave = tid >> 6, lane = tid & 63;
    const int ln = lane & 15, quad = lane >> 4;

    __shared__ __attribute__((aligned(16))) unsigned short As[64][72];
    __shared__ __attribute__((aligned(16))) unsigned short Bs[64][72];

    const int srow = tid >> 2, sc = (tid & 3) * 16;

    f32x4 acc[4];
#pragma unroll
    for (int z = 0; z < 4; z++) acc[z] = f32x4{0.f, 0.f, 0.f, 0.f};

    u32x4 ar0, ar1, br0, br1;
    {
        const unsigned short* ap = A + (long)(m0 + srow) * 1024 + sc;
        ar0 = *(const u32x4*)ap; ar1 = *(const u32x4*)(ap + 8);
        const unsigned short* bp = Bw + (long)(n0 + srow) * 1024 + sc;
        br0 = *(const u32x4*)bp; br1 = *(const u32x4*)(bp + 8);
    }

#pragma unroll 1
    for (int ks = 0; ks < 1024; ks += 64) {
        __syncthreads();
        *(u32x4*)&As[srow][sc]     = ar0;
        *(u32x4*)&As[srow][sc + 8] = ar1;
        *(u32x4*)&Bs[srow][sc]     = br0;
        *(u32x4*)&Bs[srow][sc + 8] = br1;
        __syncthreads();

        if (ks + 64 < 1024) {
            const unsigned short* ap = A + (long)(m0 + srow) * 1024 + ks + 64 + sc;
            ar0 = *(const u32x4*)ap; ar1 = *(const u32x4*)(ap + 8);
            const unsigned short* bp = Bw + (long)(n0 + srow) * 1024 + ks + 64 + sc;
            br0 = *(const u32x4*)bp; br1 = *(const u32x4*)(bp + 8);
        }

        bf16x8 bf0 = *(const bf16x8*)&Bs[wave * 16 + ln][quad * 8];
        bf16x8 bf1 = *(const bf16x8*)&Bs[wave * 16 + ln][32 + quad * 8];
#pragma unroll
        for (int mt = 0; mt < 4; mt++) {
            bf16x8 af0 = *(const bf16x8*)&As[mt * 16 + ln][quad * 8];
            bf16x8 af1 = *(const bf16x8*)&As[mt * 16 + ln][32 + quad * 8];
            acc[mt] = __builtin_amdgcn_mfma_f32_16x16x32_bf16(af0, bf0, acc[mt], 0, 0, 0);
            acc[mt] = __builtin_amdgcn_mfma_f32_16x16x32_bf16(af1, bf1, acc[mt], 0, 0, 0);
        }
    }

    int col = n0 + wave * 16 + ln;
    float bz = bias[col];
#pragma unroll
    for (int mt = 0; mt < 4; mt++)
#pragma unroll
        for (int r = 0; r < 4; r++) {
            int row = m0 + mt * 16 + quad * 4 + r;
            out[(long)row * 1024 + col] = acc[mt][r] + bz;
        }
}

extern "C" void kernel_launch(void* const* d_in, const int* in_sizes, int n_in,
                              void* d_out, int out_size, void* d_ws, size_t ws_size,
                              hipStream_t stream) {
    const float* q    = (const float*)d_in[0];
    const float* k    = (const float*)d_in[1];
    const float* v    = (const float*)d_in[2];
    const float* Wo_w = (const float*)d_in[3];
    const float* Wo_b = (const float*)d_in[4];
    float* out = (float*)d_out;

    unsigned short* ctx = (unsigned short*)d_ws;           // [4096][1024]   8.4 MB
    unsigned short* wob = ctx + (size_t)4096 * 1024;       // [1024][1024]   2.1 MB
    unsigned short* kbb = wob + (size_t)1024 * 1024;       // [32][2048][64] 8.4 MB
    unsigned short* vtb = kbb + (size_t)32 * 2048 * 64;    // [32][64][2048] 8.4 MB
    float* Opart = (float*)(vtb + (size_t)32 * 2048 * 64); // [2][32][8][64][128] 16.8 MB
    float* lpart = Opart + (size_t)2 * 32 * 8 * 64 * 128;  // [2][32][8][128]  256 KB
    int*   flags = (int*)(lpart + (size_t)2 * 32 * 8 * 128); // flags[256]

    prep_k<<<3073, 256, 0, stream>>>(k, v, Wo_w, kbb, vtb, wob, flags);
    attn_k<<<768, 256, 0, stream>>>(q, kbb, vtb, ctx, Opart, lpart, flags);
    proj_k<<<1024, 256, 0, stream>>>(ctx, wob, Wo_b, out);
}

// Round 9
// 145.471 us; speedup vs baseline: 1.2817x; 1.2817x over previous
//
#include <hip/hip_runtime.h>

typedef __attribute__((ext_vector_type(8))) short bf16x8;
typedef __attribute__((ext_vector_type(4))) float f32x4;
typedef __attribute__((ext_vector_type(4))) unsigned int u32x4;
typedef __attribute__((ext_vector_type(2))) unsigned int u32x2;
typedef __attribute__((ext_vector_type(4))) unsigned short u16x4;

#define H_ 16
#define B_ 2
#define T_ 2048
#define DH_ 64
#define MD_ 1024

static __device__ inline unsigned short f2bf(float f) {  // round-nearest-even
    union { float f; unsigned u; } x; x.f = f;
    unsigned r = (x.u + 0x7fffu + ((x.u >> 16) & 1u)) >> 16;
    return (unsigned short)r;
}
// pack two fp32 -> two bf16 (truncation), lo in low short. 1 v_perm_b32.
static __device__ inline unsigned int pack_bf2(float lo, float hi) {
    return __builtin_amdgcn_perm(__float_as_uint(hi), __float_as_uint(lo), 0x07060302u);
}
static __device__ inline float fexp2(float x) {
#if __has_builtin(__builtin_amdgcn_exp2f)
    return __builtin_amdgcn_exp2f(x);   // raw v_exp_f32
#else
    return exp2f(x);
#endif
}

// ---------------------------------------------------------------------------
// Kernel 1: prep (r4 config - measured best). blocks 0..1023: Wo fp32->bf16
// (RNE). 1024..2047: K fp32->bf16 (trunc). 2048..3071: V fp32 -> V^T bf16
// [hb][dh][T] via LDS. block 3072: zero merge flags (256 ints).
// ---------------------------------------------------------------------------
__global__ __launch_bounds__(256) void prep_k(const float* __restrict__ k,
                                              const float* __restrict__ v,
                                              const float* __restrict__ w,
                                              unsigned short* __restrict__ kb,
                                              unsigned short* __restrict__ vtb,
                                              unsigned short* __restrict__ wob,
                                              int* __restrict__ fl) {
    __shared__ __attribute__((aligned(16))) unsigned short vt64[64][64];
    const int blk = blockIdx.x;
    const int tid = threadIdx.x;
    if (blk < 1024) {
        int i = (blk * 256 + tid) * 4;
        f32x4 x = *(const f32x4*)(w + i);
        u16x4 y;
        y[0] = f2bf(x[0]); y[1] = f2bf(x[1]); y[2] = f2bf(x[2]); y[3] = f2bf(x[3]);
        *(u16x4*)(wob + i) = y;
    } else if (blk < 2048) {
        int j = blk - 1024;
        const int hb = j >> 5, s0 = (j & 31) * 64;
        const int row = tid >> 2, c = (tid & 3) * 16;
        const long off = (long)hb * (T_ * DH_) + (long)(s0 + row) * DH_ + c;
        const float* p = k + off;
        f32x4 a0 = *(const f32x4*)p;
        f32x4 a1 = *(const f32x4*)(p + 4);
        f32x4 a2 = *(const f32x4*)(p + 8);
        f32x4 a3 = *(const f32x4*)(p + 12);
        u32x4 w0, w1;
        w0[0] = pack_bf2(a0[0], a0[1]); w0[1] = pack_bf2(a0[2], a0[3]);
        w0[2] = pack_bf2(a1[0], a1[1]); w0[3] = pack_bf2(a1[2], a1[3]);
        w1[0] = pack_bf2(a2[0], a2[1]); w1[1] = pack_bf2(a2[2], a2[3]);
        w1[2] = pack_bf2(a3[0], a3[1]); w1[3] = pack_bf2(a3[2], a3[3]);
        *(u32x4*)(kb + off) = w0;
        *(u32x4*)(kb + off + 8) = w1;
    } else if (blk < 3072) {
        int j = blk - 2048;
        const int hb = j >> 5, s0 = (j & 31) * 64;
        const int vkp = tid & 31, vdg = tid >> 5;  // key-pair, dh-group
        const float* vp = v + (long)hb * (T_ * DH_) + (long)(s0 + 2 * vkp) * DH_ + vdg * 8;
        f32x4 va0 = *(const f32x4*)vp;
        f32x4 va1 = *(const f32x4*)(vp + 4);
        f32x4 vb0 = *(const f32x4*)(vp + DH_);
        f32x4 vb1 = *(const f32x4*)(vp + DH_ + 4);
#pragma unroll
        for (int jj = 0; jj < 4; jj++) {
            ((unsigned int*)&vt64[vdg * 8 + jj][0])[vkp]     = pack_bf2(va0[jj], vb0[jj]);
            ((unsigned int*)&vt64[vdg * 8 + 4 + jj][0])[vkp] = pack_bf2(va1[jj], vb1[jj]);
        }
        __syncthreads();
        const int dh = tid >> 2, kc = (tid & 3) * 16;
        u32x4 o0 = *(const u32x4*)&vt64[dh][kc];
        u32x4 o1 = *(const u32x4*)&vt64[dh][kc + 8];
        unsigned short* op = vtb + (long)hb * (DH_ * T_) + (long)dh * T_ + s0 + kc;
        *(u32x4*)op = o0;
        *(u32x4*)(op + 8) = o1;
    } else {
        for (int z = tid; z < 256; z += 256) fl[z] = 0;
    }
}

// ---------------------------------------------------------------------------
// Kernel 2: causal attention — byte-for-byte r4 (measured best, ~42us).
// 128-row q-tiles, wave = 32 q rows, swapped-operand MFMA, static CU-triple
// schedule, loser-merges split protocol.
// ---------------------------------------------------------------------------
#define SE2(t, lo, hi) ((unsigned)((t) | ((lo) << 4) | ((hi) << 10)))
__constant__ unsigned sched24[3][8] = {
    // slot 0 (largest chunk of each triple-type A..H)
    { SE2(15,0,16), SE2(7,0,16), SE2(14,0,15), SE2(14,15,30),
      SE2(13,0,14), SE2(13,14,28), SE2(12,13,26), SE2(11,12,24) },
    // slot 1
    { SE2(15,16,32), SE2(6,0,14), SE2(12,0,13), SE2(10,0,11),
      SE2(10,11,22), SE2(9,0,10), SE2(11,0,12), SE2(5,0,12) },
    // slot 2
    { SE2(0,0,2), SE2(1,0,4), SE2(2,0,6), SE2(3,0,8),
      SE2(8,0,9), SE2(9,10,20), SE2(8,9,18), SE2(4,0,10) },
};

__global__ __launch_bounds__(256, 3) void attn_k(const float* __restrict__ q,
                                                 const unsigned short* __restrict__ kb,
                                                 const unsigned short* __restrict__ vtb,
                                                 unsigned short* __restrict__ ctx,
                                                 float* __restrict__ Op,
                                                 float* __restrict__ lp,
                                                 int* __restrict__ fl) {
    const int i = blockIdx.x;
    const int xcd = i & 7, j = i >> 3;            // per-XCD stream of 96 blocks
    const int cu = j & 31, slot = j >> 5;         // 32 CUs x 3 slots
    const int type = cu >> 2, hbl = cu & 3;
    const unsigned e = sched24[slot][type];
    const int t  = (int)(e & 15u);                // tile index 0..15 (128 rows)
    const int lo = (int)((e >> 4) & 63u);
    const int hi = (int)(e >> 10);
    const int hb = xcd * 4 + hbl;                 // K/V of 4 hb stay in this XCD's L2
    const int h = hb >> 1, b = hb & 1;
    const int tid = threadIdx.x;
    const int wave = tid >> 6, lane = tid & 63;
    const int ln = lane & 15, quad = lane >> 4;

    __shared__ __attribute__((aligned(16))) unsigned short kt[64][72];    // [key][dh]
    __shared__ __attribute__((aligned(16))) unsigned short vt[64][72];    // [dh][key]
    __shared__ __attribute__((aligned(16))) unsigned short pl[4][32][72]; // per-wave P [q][key]
    __shared__ int sh_who;

    const long kbase = (long)hb * (T_ * DH_);
    const long vbase = (long)hb * (DH_ * T_);
    const int q0w = t * 128 + wave * 32;          // wave's first q row
    const int srow = tid >> 2, sc = (tid & 3) * 16;

    // Q fragments for both 16-row subtiles (RNE, 0.125*log2(e) folded)
    bf16x8 qf00, qf01, qf10, qf11;
    {
        const float qs = 0.18033688011112042f;
        const float* qp0 = q + kbase + (long)(q0w + ln) * DH_ + quad * 8;
        const float* qp1 = qp0 + 16 * DH_;
        f32x4 a0 = *(const f32x4*)qp0;
        f32x4 a1 = *(const f32x4*)(qp0 + 4);
        f32x4 b0 = *(const f32x4*)(qp0 + 32);
        f32x4 b1 = *(const f32x4*)(qp0 + 36);
        f32x4 c0 = *(const f32x4*)qp1;
        f32x4 c1 = *(const f32x4*)(qp1 + 4);
        f32x4 d0 = *(const f32x4*)(qp1 + 32);
        f32x4 d1 = *(const f32x4*)(qp1 + 36);
#pragma unroll
        for (int z = 0; z < 4; z++) {
            qf00[z]   = (short)f2bf(a0[z] * qs);
            qf00[4+z] = (short)f2bf(a1[z] * qs);
            qf01[z]   = (short)f2bf(b0[z] * qs);
            qf01[4+z] = (short)f2bf(b1[z] * qs);
            qf10[z]   = (short)f2bf(c0[z] * qs);
            qf10[4+z] = (short)f2bf(c1[z] * qs);
            qf11[z]   = (short)f2bf(d0[z] * qs);
            qf11[4+z] = (short)f2bf(d1[z] * qs);
        }
    }

    // O^T accumulators: oTu[dt][r] = O[q = q0w + u*16 + ln][dh = dt*16+quad*4+r]
    f32x4 oT0[4], oT1[4];
#pragma unroll
    for (int z = 0; z < 4; z++) { oT0[z] = f32x4{0.f,0.f,0.f,0.f}; oT1[z] = f32x4{0.f,0.f,0.f,0.f}; }
    float lsum0 = 0.f, lsum1 = 0.f;

    // prefetch first step of this chunk
    u32x4 kr0, kr1, vr0, vr1;
    {
        const unsigned short* kp = kb + kbase + (long)(lo * 64 + srow) * DH_ + sc;
        kr0 = *(const u32x4*)kp; kr1 = *(const u32x4*)(kp + 8);
        const unsigned short* vp = vtb + vbase + (long)srow * T_ + lo * 64 + sc;
        vr0 = *(const u32x4*)vp; vr1 = *(const u32x4*)(vp + 8);
    }

#pragma unroll 1
    for (int step = lo; step < hi; step++) {
        __syncthreads();
        *(u32x4*)&kt[srow][sc]     = kr0;
        *(u32x4*)&kt[srow][sc + 8] = kr1;
        *(u32x4*)&vt[srow][sc]     = vr0;
        *(u32x4*)&vt[srow][sc + 8] = vr1;
        __syncthreads();

        if (step + 1 < hi) {
            const unsigned short* kp = kb + kbase + (long)((step + 1) * 64 + srow) * DH_ + sc;
            kr0 = *(const u32x4*)kp; kr1 = *(const u32x4*)(kp + 8);
            const unsigned short* vp = vtb + vbase + (long)srow * T_ + (step + 1) * 64 + sc;
            vr0 = *(const u32x4*)vp; vr1 = *(const u32x4*)(vp + 8);
        }

        if (step * 64 <= q0w + 31) {              // else: wave fully masked, skip compute
            const bool dmask = (step * 64 + 63 > q0w);   // diagonal touches this wave
            const int dbase = step * 64 + quad * 4 - q0w - ln;

            // QK^T (shared K-frags across both q-subtiles), exp2, mask, pack -> pl
#pragma unroll
            for (int nt = 0; nt < 4; nt++) {
                bf16x8 kf0 = *(const bf16x8*)&kt[nt * 16 + ln][quad * 8];
                bf16x8 kf1 = *(const bf16x8*)&kt[nt * 16 + ln][32 + quad * 8];
                f32x4 a0 = f32x4{0.f,0.f,0.f,0.f};
                a0 = __builtin_amdgcn_mfma_f32_16x16x32_bf16(kf0, qf00, a0, 0, 0, 0);
                a0 = __builtin_amdgcn_mfma_f32_16x16x32_bf16(kf1, qf01, a0, 0, 0, 0);
                f32x4 a1 = f32x4{0.f,0.f,0.f,0.f};
                a1 = __builtin_amdgcn_mfma_f32_16x16x32_bf16(kf0, qf10, a1, 0, 0, 0);
                a1 = __builtin_amdgcn_mfma_f32_16x16x32_bf16(kf1, qf11, a1, 0, 0, 0);
#pragma unroll
                for (int r = 0; r < 4; r++) { a0[r] = fexp2(a0[r]); a1[r] = fexp2(a1[r]); }
                if (dmask) {
#pragma unroll
                    for (int r = 0; r < 4; r++) {
                        if (dbase + nt * 16 + r > 0)  a0[r] = 0.f;
                        if (dbase + nt * 16 + r > 16) a1[r] = 0.f;
                    }
                }
                lsum0 += (a0[0] + a0[1]) + (a0[2] + a0[3]);
                lsum1 += (a1[0] + a1[1]) + (a1[2] + a1[3]);
                u32x2 w0, w1;
                w0[0] = pack_bf2(a0[0], a0[1]); w0[1] = pack_bf2(a0[2], a0[3]);
                w1[0] = pack_bf2(a1[0], a1[1]); w1[1] = pack_bf2(a1[2], a1[3]);
                *(u32x2*)&pl[wave][ln][nt * 16 + quad * 4]      = w0;
                *(u32x2*)&pl[wave][16 + ln][nt * 16 + quad * 4] = w1;
            }

            // per-wave buffer: in-wave DS ordering + lgkmcnt, no barrier needed
            bf16x8 pf00 = *(const bf16x8*)&pl[wave][ln][quad * 8];
            bf16x8 pf01 = *(const bf16x8*)&pl[wave][ln][32 + quad * 8];
            bf16x8 pf10 = *(const bf16x8*)&pl[wave][16 + ln][quad * 8];
            bf16x8 pf11 = *(const bf16x8*)&pl[wave][16 + ln][32 + quad * 8];

            // PV (shared V-frags): oTu[dt] += V^T . P_u
#pragma unroll
            for (int dt = 0; dt < 4; dt++) {
                bf16x8 vf0 = *(const bf16x8*)&vt[dt * 16 + ln][quad * 8];
                bf16x8 vf1 = *(const bf16x8*)&vt[dt * 16 + ln][32 + quad * 8];
                oT0[dt] = __builtin_amdgcn_mfma_f32_16x16x32_bf16(vf0, pf00, oT0[dt], 0, 0, 0);
                oT0[dt] = __builtin_amdgcn_mfma_f32_16x16x32_bf16(vf1, pf01, oT0[dt], 0, 0, 0);
                oT1[dt] = __builtin_amdgcn_mfma_f32_16x16x32_bf16(vf0, pf10, oT1[dt], 0, 0, 0);
                oT1[dt] = __builtin_amdgcn_mfma_f32_16x16x32_bf16(vf1, pf11, oT1[dt], 0, 0, 0);
            }
        }
    }

    // full row-sums (keys were split across quads)
    lsum0 += __shfl_xor(lsum0, 16); lsum0 += __shfl_xor(lsum0, 32);
    lsum1 += __shfl_xor(lsum1, 16); lsum1 += __shfl_xor(lsum1, 32);

    float rl0, rl1;
    if (t < 8) {
        rl0 = __builtin_amdgcn_rcpf(lsum0);
        rl1 = __builtin_amdgcn_rcpf(lsum1);
    } else {
        // split tile: publish partial in O^T slab [dh][q] (coalesced 64B per quad)
        const int c = (lo != 0) ? 1 : 0;
        const long slab = ((long)c * 32 + hb) * 8 + (t - 8);
        float* ob = Op + slab * 8192;
        const int ql0 = wave * 32 + ln, ql1 = ql0 + 16;
#pragma unroll
        for (int dt = 0; dt < 4; dt++)
#pragma unroll
            for (int r = 0; r < 4; r++) {
                const int dh = dt * 16 + quad * 4 + r;
                __hip_atomic_store(&ob[dh * 128 + ql0], oT0[dt][r],
                                   __ATOMIC_RELAXED, __HIP_MEMORY_SCOPE_AGENT);
                __hip_atomic_store(&ob[dh * 128 + ql1], oT1[dt][r],
                                   __ATOMIC_RELAXED, __HIP_MEMORY_SCOPE_AGENT);
            }
        if (quad == 0) {
            __hip_atomic_store(&lp[slab * 128 + ql0], lsum0,
                               __ATOMIC_RELAXED, __HIP_MEMORY_SCOPE_AGENT);
            __hip_atomic_store(&lp[slab * 128 + ql1], lsum1,
                               __ATOMIC_RELAXED, __HIP_MEMORY_SCOPE_AGENT);
        }
        __syncthreads();   // drains each wave's vmcnt -> partials visible at agent scope
        if (tid == 0)
            sh_who = __hip_atomic_fetch_add(&fl[hb * 8 + (t - 8)], 1,
                                            __ATOMIC_RELAXED, __HIP_MEMORY_SCOPE_AGENT);
        __syncthreads();
        if (sh_who != 1) return;   // first finisher exits; loser merges (block-uniform)
        const long slab2 = ((long)(c ^ 1) * 32 + hb) * 8 + (t - 8);
        const float* qb = Op + slab2 * 8192;
#pragma unroll
        for (int dt = 0; dt < 4; dt++)
#pragma unroll
            for (int r = 0; r < 4; r++) {
                const int dh = dt * 16 + quad * 4 + r;
                oT0[dt][r] += __hip_atomic_load(&qb[dh * 128 + ql0],
                                                __ATOMIC_RELAXED, __HIP_MEMORY_SCOPE_AGENT);
                oT1[dt][r] += __hip_atomic_load(&qb[dh * 128 + ql1],
                                                __ATOMIC_RELAXED, __HIP_MEMORY_SCOPE_AGENT);
            }
        lsum0 += __hip_atomic_load(&lp[slab2 * 128 + ql0],
                                   __ATOMIC_RELAXED, __HIP_MEMORY_SCOPE_AGENT);
        lsum1 += __hip_atomic_load(&lp[slab2 * 128 + ql1],
                                   __ATOMIC_RELAXED, __HIP_MEMORY_SCOPE_AGENT);
        rl0 = __builtin_amdgcn_rcpf(lsum0);
        rl1 = __builtin_amdgcn_rcpf(lsum1);
    }

    // epilogue: scale, pack bf16 (RNE), transpose via own-wave pl region
    // (in-wave DS ordering, no barrier), then coalesced 16B ctx stores.
#pragma unroll
    for (int dt = 0; dt < 4; dt++) {
        u16x4 y0, y1;
        y0[0] = f2bf(oT0[dt][0] * rl0); y0[1] = f2bf(oT0[dt][1] * rl0);
        y0[2] = f2bf(oT0[dt][2] * rl0); y0[3] = f2bf(oT0[dt][3] * rl0);
        y1[0] = f2bf(oT1[dt][0] * rl1); y1[1] = f2bf(oT1[dt][1] * rl1);
        y1[2] = f2bf(oT1[dt][2] * rl1); y1[3] = f2bf(oT1[dt][3] * rl1);
        *(u16x4*)&pl[wave][ln][dt * 16 + quad * 4]      = y0;
        *(u16x4*)&pl[wave][16 + ln][dt * 16 + quad * 4] = y1;
    }
    const int rr = lane >> 1, cc = (lane & 1) * 32;
    u32x4 z0 = *(const u32x4*)&pl[wave][rr][cc];
    u32x4 z1 = *(const u32x4*)&pl[wave][rr][cc + 8];
    u32x4 z2 = *(const u32x4*)&pl[wave][rr][cc + 16];
    u32x4 z3 = *(const u32x4*)&pl[wave][rr][cc + 24];
    unsigned short* cp = ctx + (long)(b * T_ + t * 128 + wave * 32 + rr) * MD_ + h * 64 + cc;
    *(u32x4*)cp = z0;
    *(u32x4*)(cp + 8) = z1;
    *(u32x4*)(cp + 16) = z2;
    *(u32x4*)(cp + 24) = z3;
}

// ---------------------------------------------------------------------------
// Kernel 3: projection GEMM, BM=128 BN=64 BK=64. Grid 512 blocks (2/CU).
// 4 waves in 2x2: each wave 64 rows x 32 cols (4x2 fragments).
// STAGING FIXED vs r8: A = 128x64 el -> 2 thr/row x 4 u32x4 (32 el/thr);
// B = 64x64 el -> 4 thr/row x 2 u32x4 (16 el/thr). Audit: 256*32=8192=As,
// 256*16=4096=Bs. XCD n-affinity kept (Wo slice 256 KB L2-resident).
// ---------------------------------------------------------------------------
__global__ __launch_bounds__(256, 2) void proj_k(const unsigned short* __restrict__ A,
                                                 const unsigned short* __restrict__ Bw,
                                                 const float* __restrict__ bias,
                                                 float* __restrict__ out) {
    const int i = blockIdx.x;
    const int n0 = ((i & 7) * 2 + ((i >> 3) & 1)) * 64;
    const int m0 = (i >> 4) * 128;
    const int tid = threadIdx.x;
    const int wave = tid >> 6, lane = tid & 63;
    const int ln = lane & 15, quad = lane >> 4;
    const int wm = (wave & 1) * 64, wn = (wave >> 1) * 32;

    __shared__ __attribute__((aligned(16))) unsigned short As[128][72];
    __shared__ __attribute__((aligned(16))) unsigned short Bs[64][72];

    // A staging: 2 threads/row, 32 cols each (4 x 8-el vectors).
    // B staging: 4 threads/row, 16 cols each (2 x 8-el vectors).
    const int arow = tid >> 1, acol = (tid & 1) * 32;
    const int brow = tid >> 2, bcol = (tid & 3) * 16;

    f32x4 acc[4][2];
#pragma unroll
    for (int mt = 0; mt < 4; mt++)
#pragma unroll
        for (int nt = 0; nt < 2; nt++) acc[mt][nt] = f32x4{0.f, 0.f, 0.f, 0.f};

    u32x4 ar0, ar1, ar2, ar3, br0, br1;
    {
        const unsigned short* ap = A + (long)(m0 + arow) * 1024 + acol;
        ar0 = *(const u32x4*)ap;        ar1 = *(const u32x4*)(ap + 8);
        ar2 = *(const u32x4*)(ap + 16); ar3 = *(const u32x4*)(ap + 24);
        const unsigned short* bp = Bw + (long)(n0 + brow) * 1024 + bcol;
        br0 = *(const u32x4*)bp; br1 = *(const u32x4*)(bp + 8);
    }

#pragma unroll 1
    for (int ks = 0; ks < 1024; ks += 64) {
        __syncthreads();
        *(u32x4*)&As[arow][acol]      = ar0;
        *(u32x4*)&As[arow][acol + 8]  = ar1;
        *(u32x4*)&As[arow][acol + 16] = ar2;
        *(u32x4*)&As[arow][acol + 24] = ar3;
        *(u32x4*)&Bs[brow][bcol]      = br0;
        *(u32x4*)&Bs[brow][bcol + 8]  = br1;
        __syncthreads();

        if (ks + 64 < 1024) {
            const unsigned short* ap = A + (long)(m0 + arow) * 1024 + ks + 64 + acol;
            ar0 = *(const u32x4*)ap;        ar1 = *(const u32x4*)(ap + 8);
            ar2 = *(const u32x4*)(ap + 16); ar3 = *(const u32x4*)(ap + 24);
            const unsigned short* bp = Bw + (long)(n0 + brow) * 1024 + ks + 64 + bcol;
            br0 = *(const u32x4*)bp; br1 = *(const u32x4*)(bp + 8);
        }

        bf16x8 bf[2][2];
#pragma unroll
        for (int nt = 0; nt < 2; nt++) {
            bf[nt][0] = *(const bf16x8*)&Bs[wn + nt * 16 + ln][quad * 8];
            bf[nt][1] = *(const bf16x8*)&Bs[wn + nt * 16 + ln][32 + quad * 8];
        }
#pragma unroll
        for (int mt = 0; mt < 4; mt++) {
            bf16x8 af0 = *(const bf16x8*)&As[wm + mt * 16 + ln][quad * 8];
            bf16x8 af1 = *(const bf16x8*)&As[wm + mt * 16 + ln][32 + quad * 8];
#pragma unroll
            for (int nt = 0; nt < 2; nt++) {
                acc[mt][nt] = __builtin_amdgcn_mfma_f32_16x16x32_bf16(af0, bf[nt][0], acc[mt][nt], 0, 0, 0);
                acc[mt][nt] = __builtin_amdgcn_mfma_f32_16x16x32_bf16(af1, bf[nt][1], acc[mt][nt], 0, 0, 0);
            }
        }
    }

#pragma unroll
    for (int nt = 0; nt < 2; nt++) {
        int col = n0 + wn + nt * 16 + ln;
        float bz = bias[col];
#pragma unroll
        for (int mt = 0; mt < 4; mt++)
#pragma unroll
            for (int r = 0; r < 4; r++) {
                int row = m0 + wm + mt * 16 + quad * 4 + r;
                out[(long)row * 1024 + col] = acc[mt][nt][r] + bz;
            }
    }
}

extern "C" void kernel_launch(void* const* d_in, const int* in_sizes, int n_in,
                              void* d_out, int out_size, void* d_ws, size_t ws_size,
                              hipStream_t stream) {
    const float* q    = (const float*)d_in[0];
    const float* k    = (const float*)d_in[1];
    const float* v    = (const float*)d_in[2];
    const float* Wo_w = (const float*)d_in[3];
    const float* Wo_b = (const float*)d_in[4];
    float* out = (float*)d_out;

    unsigned short* ctx = (unsigned short*)d_ws;           // [4096][1024]   8.4 MB
    unsigned short* wob = ctx + (size_t)4096 * 1024;       // [1024][1024]   2.1 MB
    unsigned short* kbb = wob + (size_t)1024 * 1024;       // [32][2048][64] 8.4 MB
    unsigned short* vtb = kbb + (size_t)32 * 2048 * 64;    // [32][64][2048] 8.4 MB
    float* Opart = (float*)(vtb + (size_t)32 * 2048 * 64); // [2][32][8][64][128] 16.8 MB
    float* lpart = Opart + (size_t)2 * 32 * 8 * 64 * 128;  // [2][32][8][128]  256 KB
    int*   flags = (int*)(lpart + (size_t)2 * 32 * 8 * 128); // flags[256]

    prep_k<<<3073, 256, 0, stream>>>(k, v, Wo_w, kbb, vtb, wob, flags);
    attn_k<<<768, 256, 0, stream>>>(q, kbb, vtb, ctx, Opart, lpart, flags);
    proj_k<<<512, 256, 0, stream>>>(ctx, wob, Wo_b, out);
}

// Round 10
// 144.185 us; speedup vs baseline: 1.2932x; 1.0089x over previous
//
#include <hip/hip_runtime.h>

typedef __attribute__((ext_vector_type(8))) short bf16x8;
typedef __attribute__((ext_vector_type(4))) float f32x4;
typedef __attribute__((ext_vector_type(4))) unsigned int u32x4;
typedef __attribute__((ext_vector_type(2))) unsigned int u32x2;
typedef __attribute__((ext_vector_type(4))) unsigned short u16x4;

#define H_ 16
#define B_ 2
#define T_ 2048
#define DH_ 64
#define MD_ 1024

static __device__ inline unsigned short f2bf(float f) {  // round-nearest-even
    union { float f; unsigned u; } x; x.f = f;
    unsigned r = (x.u + 0x7fffu + ((x.u >> 16) & 1u)) >> 16;
    return (unsigned short)r;
}
// pack two fp32 -> two bf16 (truncation), lo in low short. 1 v_perm_b32.
static __device__ inline unsigned int pack_bf2(float lo, float hi) {
    return __builtin_amdgcn_perm(__float_as_uint(hi), __float_as_uint(lo), 0x07060302u);
}
static __device__ inline float fexp2(float x) {
#if __has_builtin(__builtin_amdgcn_exp2f)
    return __builtin_amdgcn_exp2f(x);   // raw v_exp_f32
#else
    return exp2f(x);
#endif
}

// ---------------------------------------------------------------------------
// Kernel 1: prep. blocks 0..1023: Wo fp32->bf16 (RNE). 1024..2047: K fp32->bf16
// (trunc). 2048..3071: V fp32 -> V^T bf16 [hb][dh][T] via LDS. block 3072:
// zero merge flags (512 ints: one per (hb, tile)).
// ---------------------------------------------------------------------------
__global__ __launch_bounds__(256) void prep_k(const float* __restrict__ k,
                                              const float* __restrict__ v,
                                              const float* __restrict__ w,
                                              unsigned short* __restrict__ kb,
                                              unsigned short* __restrict__ vtb,
                                              unsigned short* __restrict__ wob,
                                              int* __restrict__ fl) {
    __shared__ __attribute__((aligned(16))) unsigned short vt64[64][64];
    const int blk = blockIdx.x;
    const int tid = threadIdx.x;
    if (blk < 1024) {
        int i = (blk * 256 + tid) * 4;
        f32x4 x = *(const f32x4*)(w + i);
        u16x4 y;
        y[0] = f2bf(x[0]); y[1] = f2bf(x[1]); y[2] = f2bf(x[2]); y[3] = f2bf(x[3]);
        *(u16x4*)(wob + i) = y;
    } else if (blk < 2048) {
        int j = blk - 1024;
        const int hb = j >> 5, s0 = (j & 31) * 64;
        const int row = tid >> 2, c = (tid & 3) * 16;
        const long off = (long)hb * (T_ * DH_) + (long)(s0 + row) * DH_ + c;
        const float* p = k + off;
        f32x4 a0 = *(const f32x4*)p;
        f32x4 a1 = *(const f32x4*)(p + 4);
        f32x4 a2 = *(const f32x4*)(p + 8);
        f32x4 a3 = *(const f32x4*)(p + 12);
        u32x4 w0, w1;
        w0[0] = pack_bf2(a0[0], a0[1]); w0[1] = pack_bf2(a0[2], a0[3]);
        w0[2] = pack_bf2(a1[0], a1[1]); w0[3] = pack_bf2(a1[2], a1[3]);
        w1[0] = pack_bf2(a2[0], a2[1]); w1[1] = pack_bf2(a2[2], a2[3]);
        w1[2] = pack_bf2(a3[0], a3[1]); w1[3] = pack_bf2(a3[2], a3[3]);
        *(u32x4*)(kb + off) = w0;
        *(u32x4*)(kb + off + 8) = w1;
    } else if (blk < 3072) {
        int j = blk - 2048;
        const int hb = j >> 5, s0 = (j & 31) * 64;
        const int vkp = tid & 31, vdg = tid >> 5;  // key-pair, dh-group
        const float* vp = v + (long)hb * (T_ * DH_) + (long)(s0 + 2 * vkp) * DH_ + vdg * 8;
        f32x4 va0 = *(const f32x4*)vp;
        f32x4 va1 = *(const f32x4*)(vp + 4);
        f32x4 vb0 = *(const f32x4*)(vp + DH_);
        f32x4 vb1 = *(const f32x4*)(vp + DH_ + 4);
#pragma unroll
        for (int jj = 0; jj < 4; jj++) {
            ((unsigned int*)&vt64[vdg * 8 + jj][0])[vkp]     = pack_bf2(va0[jj], vb0[jj]);
            ((unsigned int*)&vt64[vdg * 8 + 4 + jj][0])[vkp] = pack_bf2(va1[jj], vb1[jj]);
        }
        __syncthreads();
        const int dh = tid >> 2, kc = (tid & 3) * 16;
        u32x4 o0 = *(const u32x4*)&vt64[dh][kc];
        u32x4 o1 = *(const u32x4*)&vt64[dh][kc + 8];
        unsigned short* op = vtb + (long)hb * (DH_ * T_) + (long)dh * T_ + s0 + kc;
        *(u32x4*)op = o0;
        *(u32x4*)(op + 8) = o1;
    } else {
        for (int z = tid; z < 512; z += 256) fl[z] = 0;
    }
}

// ---------------------------------------------------------------------------
// Kernel 2: causal attention. Inner loop byte-identical to r4/r9 (measured
// best). THIS ROUND: 4 blocks/CU (was 3). Every tile t splits into halves
// [0,t+1) and [t+1,2t+2); CU type tau takes both halves of tile 15-tau AND
// both halves of tile tau: 2(16-tau)+2(tau+1) = 34 steps/CU, exact balance.
// 128 blocks/XCD = 4/CU co-resident (LDS 37.4KB x4 = 149.5 <= 160KB,
// VGPR 68 <= 128) -> 16 waves/CU for latency hiding. Merge partners are
// CU-co-located (L2-local partials). All tiles use the validated
// loser-merges protocol (2-term fp add commutative => numerics unchanged).
// ---------------------------------------------------------------------------
#define SE2(t, lo, hi) ((unsigned)((t) | ((lo) << 4) | ((hi) << 10)))
__constant__ unsigned sched32[4][8] = {
    // slot 0: first half of tile 15-tau (size 16-tau)
    { SE2(15,0,16), SE2(14,0,15), SE2(13,0,14), SE2(12,0,13),
      SE2(11,0,12), SE2(10,0,11), SE2(9,0,10),  SE2(8,0,9) },
    // slot 1: second half of tile 15-tau (size 16-tau)
    { SE2(15,16,32), SE2(14,15,30), SE2(13,14,28), SE2(12,13,26),
      SE2(11,12,24), SE2(10,11,22), SE2(9,10,20),  SE2(8,9,18) },
    // slot 2: first half of tile tau (size tau+1)
    { SE2(0,0,1), SE2(1,0,2), SE2(2,0,3), SE2(3,0,4),
      SE2(4,0,5), SE2(5,0,6), SE2(6,0,7), SE2(7,0,8) },
    // slot 3: second half of tile tau (size tau+1)
    { SE2(0,1,2), SE2(1,2,4), SE2(2,3,6), SE2(3,4,8),
      SE2(4,5,10), SE2(5,6,12), SE2(6,7,14), SE2(7,8,16) },
};

__global__ __launch_bounds__(256, 4) void attn_k(const float* __restrict__ q,
                                                 const unsigned short* __restrict__ kb,
                                                 const unsigned short* __restrict__ vtb,
                                                 unsigned short* __restrict__ ctx,
                                                 float* __restrict__ Op,
                                                 float* __restrict__ lp,
                                                 int* __restrict__ fl) {
    const int i = blockIdx.x;
    const int xcd = i & 7, j = i >> 3;            // per-XCD stream of 128 blocks
    const int cu = j & 31, slot = j >> 5;         // 32 CUs x 4 slots
    const int type = cu >> 2, hbl = cu & 3;
    const unsigned e = sched32[slot][type];
    const int t  = (int)(e & 15u);                // tile index 0..15 (128 rows)
    const int lo = (int)((e >> 4) & 63u);
    const int hi = (int)(e >> 10);
    const int hb = xcd * 4 + hbl;                 // K/V of 4 hb stay in this XCD's L2
    const int h = hb >> 1, b = hb & 1;
    const int tid = threadIdx.x;
    const int wave = tid >> 6, lane = tid & 63;
    const int ln = lane & 15, quad = lane >> 4;

    __shared__ __attribute__((aligned(16))) unsigned short kt[64][72];    // [key][dh]
    __shared__ __attribute__((aligned(16))) unsigned short vt[64][72];    // [dh][key]
    __shared__ __attribute__((aligned(16))) unsigned short pl[4][32][72]; // per-wave P [q][key]
    __shared__ int sh_who;

    const long kbase = (long)hb * (T_ * DH_);
    const long vbase = (long)hb * (DH_ * T_);
    const int q0w = t * 128 + wave * 32;          // wave's first q row
    const int srow = tid >> 2, sc = (tid & 3) * 16;

    // Q fragments for both 16-row subtiles (RNE, 0.125*log2(e) folded)
    bf16x8 qf00, qf01, qf10, qf11;
    {
        const float qs = 0.18033688011112042f;
        const float* qp0 = q + kbase + (long)(q0w + ln) * DH_ + quad * 8;
        const float* qp1 = qp0 + 16 * DH_;
        f32x4 a0 = *(const f32x4*)qp0;
        f32x4 a1 = *(const f32x4*)(qp0 + 4);
        f32x4 b0 = *(const f32x4*)(qp0 + 32);
        f32x4 b1 = *(const f32x4*)(qp0 + 36);
        f32x4 c0 = *(const f32x4*)qp1;
        f32x4 c1 = *(const f32x4*)(qp1 + 4);
        f32x4 d0 = *(const f32x4*)(qp1 + 32);
        f32x4 d1 = *(const f32x4*)(qp1 + 36);
#pragma unroll
        for (int z = 0; z < 4; z++) {
            qf00[z]   = (short)f2bf(a0[z] * qs);
            qf00[4+z] = (short)f2bf(a1[z] * qs);
            qf01[z]   = (short)f2bf(b0[z] * qs);
            qf01[4+z] = (short)f2bf(b1[z] * qs);
            qf10[z]   = (short)f2bf(c0[z] * qs);
            qf10[4+z] = (short)f2bf(c1[z] * qs);
            qf11[z]   = (short)f2bf(d0[z] * qs);
            qf11[4+z] = (short)f2bf(d1[z] * qs);
        }
    }

    // O^T accumulators: oTu[dt][r] = O[q = q0w + u*16 + ln][dh = dt*16+quad*4+r]
    f32x4 oT0[4], oT1[4];
#pragma unroll
    for (int z = 0; z < 4; z++) { oT0[z] = f32x4{0.f,0.f,0.f,0.f}; oT1[z] = f32x4{0.f,0.f,0.f,0.f}; }
    float lsum0 = 0.f, lsum1 = 0.f;

    // prefetch first step of this chunk
    u32x4 kr0, kr1, vr0, vr1;
    {
        const unsigned short* kp = kb + kbase + (long)(lo * 64 + srow) * DH_ + sc;
        kr0 = *(const u32x4*)kp; kr1 = *(const u32x4*)(kp + 8);
        const unsigned short* vp = vtb + vbase + (long)srow * T_ + lo * 64 + sc;
        vr0 = *(const u32x4*)vp; vr1 = *(const u32x4*)(vp + 8);
    }

#pragma unroll 1
    for (int step = lo; step < hi; step++) {
        __syncthreads();
        *(u32x4*)&kt[srow][sc]     = kr0;
        *(u32x4*)&kt[srow][sc + 8] = kr1;
        *(u32x4*)&vt[srow][sc]     = vr0;
        *(u32x4*)&vt[srow][sc + 8] = vr1;
        __syncthreads();

        if (step + 1 < hi) {
            const unsigned short* kp = kb + kbase + (long)((step + 1) * 64 + srow) * DH_ + sc;
            kr0 = *(const u32x4*)kp; kr1 = *(const u32x4*)(kp + 8);
            const unsigned short* vp = vtb + vbase + (long)srow * T_ + (step + 1) * 64 + sc;
            vr0 = *(const u32x4*)vp; vr1 = *(const u32x4*)(vp + 8);
        }

        if (step * 64 <= q0w + 31) {              // else: wave fully masked, skip compute
            const bool dmask = (step * 64 + 63 > q0w);   // diagonal touches this wave
            const int dbase = step * 64 + quad * 4 - q0w - ln;

            // QK^T (shared K-frags across both q-subtiles), exp2, mask, pack -> pl
#pragma unroll
            for (int nt = 0; nt < 4; nt++) {
                bf16x8 kf0 = *(const bf16x8*)&kt[nt * 16 + ln][quad * 8];
                bf16x8 kf1 = *(const bf16x8*)&kt[nt * 16 + ln][32 + quad * 8];
                f32x4 a0 = f32x4{0.f,0.f,0.f,0.f};
                a0 = __builtin_amdgcn_mfma_f32_16x16x32_bf16(kf0, qf00, a0, 0, 0, 0);
                a0 = __builtin_amdgcn_mfma_f32_16x16x32_bf16(kf1, qf01, a0, 0, 0, 0);
                f32x4 a1 = f32x4{0.f,0.f,0.f,0.f};
                a1 = __builtin_amdgcn_mfma_f32_16x16x32_bf16(kf0, qf10, a1, 0, 0, 0);
                a1 = __builtin_amdgcn_mfma_f32_16x16x32_bf16(kf1, qf11, a1, 0, 0, 0);
#pragma unroll
                for (int r = 0; r < 4; r++) { a0[r] = fexp2(a0[r]); a1[r] = fexp2(a1[r]); }
                if (dmask) {
#pragma unroll
                    for (int r = 0; r < 4; r++) {
                        if (dbase + nt * 16 + r > 0)  a0[r] = 0.f;
                        if (dbase + nt * 16 + r > 16) a1[r] = 0.f;
                    }
                }
                lsum0 += (a0[0] + a0[1]) + (a0[2] + a0[3]);
                lsum1 += (a1[0] + a1[1]) + (a1[2] + a1[3]);
                u32x2 w0, w1;
                w0[0] = pack_bf2(a0[0], a0[1]); w0[1] = pack_bf2(a0[2], a0[3]);
                w1[0] = pack_bf2(a1[0], a1[1]); w1[1] = pack_bf2(a1[2], a1[3]);
                *(u32x2*)&pl[wave][ln][nt * 16 + quad * 4]      = w0;
                *(u32x2*)&pl[wave][16 + ln][nt * 16 + quad * 4] = w1;
            }

            // per-wave buffer: in-wave DS ordering + lgkmcnt, no barrier needed
            bf16x8 pf00 = *(const bf16x8*)&pl[wave][ln][quad * 8];
            bf16x8 pf01 = *(const bf16x8*)&pl[wave][ln][32 + quad * 8];
            bf16x8 pf10 = *(const bf16x8*)&pl[wave][16 + ln][quad * 8];
            bf16x8 pf11 = *(const bf16x8*)&pl[wave][16 + ln][32 + quad * 8];

            // PV (shared V-frags): oTu[dt] += V^T . P_u
#pragma unroll
            for (int dt = 0; dt < 4; dt++) {
                bf16x8 vf0 = *(const bf16x8*)&vt[dt * 16 + ln][quad * 8];
                bf16x8 vf1 = *(const bf16x8*)&vt[dt * 16 + ln][32 + quad * 8];
                oT0[dt] = __builtin_amdgcn_mfma_f32_16x16x32_bf16(vf0, pf00, oT0[dt], 0, 0, 0);
                oT0[dt] = __builtin_amdgcn_mfma_f32_16x16x32_bf16(vf1, pf01, oT0[dt], 0, 0, 0);
                oT1[dt] = __builtin_amdgcn_mfma_f32_16x16x32_bf16(vf0, pf10, oT1[dt], 0, 0, 0);
                oT1[dt] = __builtin_amdgcn_mfma_f32_16x16x32_bf16(vf1, pf11, oT1[dt], 0, 0, 0);
            }
        }
    }

    // full row-sums (keys were split across quads)
    lsum0 += __shfl_xor(lsum0, 16); lsum0 += __shfl_xor(lsum0, 32);
    lsum1 += __shfl_xor(lsum1, 16); lsum1 += __shfl_xor(lsum1, 32);

    // every tile is split: publish partial in O^T slab [dh][q], loser merges
    const int c = (lo != 0) ? 1 : 0;
    const long slab = ((long)c * 32 + hb) * 16 + t;
    float* ob = Op + slab * 8192;
    const int ql0 = wave * 32 + ln, ql1 = ql0 + 16;
#pragma unroll
    for (int dt = 0; dt < 4; dt++)
#pragma unroll
        for (int r = 0; r < 4; r++) {
            const int dh = dt * 16 + quad * 4 + r;
            __hip_atomic_store(&ob[dh * 128 + ql0], oT0[dt][r],
                               __ATOMIC_RELAXED, __HIP_MEMORY_SCOPE_AGENT);
            __hip_atomic_store(&ob[dh * 128 + ql1], oT1[dt][r],
                               __ATOMIC_RELAXED, __HIP_MEMORY_SCOPE_AGENT);
        }
    if (quad == 0) {
        __hip_atomic_store(&lp[slab * 128 + ql0], lsum0,
                           __ATOMIC_RELAXED, __HIP_MEMORY_SCOPE_AGENT);
        __hip_atomic_store(&lp[slab * 128 + ql1], lsum1,
                           __ATOMIC_RELAXED, __HIP_MEMORY_SCOPE_AGENT);
    }
    __syncthreads();   // drains each wave's vmcnt -> partials visible at agent scope
    if (tid == 0)
        sh_who = __hip_atomic_fetch_add(&fl[hb * 16 + t], 1,
                                        __ATOMIC_RELAXED, __HIP_MEMORY_SCOPE_AGENT);
    __syncthreads();
    if (sh_who != 1) return;   // first finisher exits; loser merges (block-uniform)
    const long slab2 = ((long)(c ^ 1) * 32 + hb) * 16 + t;
    const float* qb = Op + slab2 * 8192;
#pragma unroll
    for (int dt = 0; dt < 4; dt++)
#pragma unroll
        for (int r = 0; r < 4; r++) {
            const int dh = dt * 16 + quad * 4 + r;
            oT0[dt][r] += __hip_atomic_load(&qb[dh * 128 + ql0],
                                            __ATOMIC_RELAXED, __HIP_MEMORY_SCOPE_AGENT);
            oT1[dt][r] += __hip_atomic_load(&qb[dh * 128 + ql1],
                                            __ATOMIC_RELAXED, __HIP_MEMORY_SCOPE_AGENT);
        }
    lsum0 += __hip_atomic_load(&lp[slab2 * 128 + ql0],
                               __ATOMIC_RELAXED, __HIP_MEMORY_SCOPE_AGENT);
    lsum1 += __hip_atomic_load(&lp[slab2 * 128 + ql1],
                               __ATOMIC_RELAXED, __HIP_MEMORY_SCOPE_AGENT);
    float rl0 = __builtin_amdgcn_rcpf(lsum0);
    float rl1 = __builtin_amdgcn_rcpf(lsum1);

    // epilogue: scale, pack bf16 (RNE), transpose via own-wave pl region
    // (in-wave DS ordering, no barrier), then coalesced 16B ctx stores.
#pragma unroll
    for (int dt = 0; dt < 4; dt++) {
        u16x4 y0, y1;
        y0[0] = f2bf(oT0[dt][0] * rl0); y0[1] = f2bf(oT0[dt][1] * rl0);
        y0[2] = f2bf(oT0[dt][2] * rl0); y0[3] = f2bf(oT0[dt][3] * rl0);
        y1[0] = f2bf(oT1[dt][0] * rl1); y1[1] = f2bf(oT1[dt][1] * rl1);
        y1[2] = f2bf(oT1[dt][2] * rl1); y1[3] = f2bf(oT1[dt][3] * rl1);
        *(u16x4*)&pl[wave][ln][dt * 16 + quad * 4]      = y0;
        *(u16x4*)&pl[wave][16 + ln][dt * 16 + quad * 4] = y1;
    }
    const int rr = lane >> 1, cc = (lane & 1) * 32;
    u32x4 z0 = *(const u32x4*)&pl[wave][rr][cc];
    u32x4 z1 = *(const u32x4*)&pl[wave][rr][cc + 8];
    u32x4 z2 = *(const u32x4*)&pl[wave][rr][cc + 16];
    u32x4 z3 = *(const u32x4*)&pl[wave][rr][cc + 24];
    unsigned short* cp = ctx + (long)(b * T_ + t * 128 + wave * 32 + rr) * MD_ + h * 64 + cc;
    *(u32x4*)cp = z0;
    *(u32x4*)(cp + 8) = z1;
    *(u32x4*)(cp + 16) = z2;
    *(u32x4*)(cp + 24) = z3;
}

// ---------------------------------------------------------------------------
// Kernel 3: projection GEMM, BM=128 BN=64 BK=64 (r9 config, measured win).
// Grid 512 blocks (2/CU). 4 waves in 2x2: each wave 64 rows x 32 cols.
// XCD n-affinity: each XCD owns 2 n-tiles (Wo slice 256 KB L2-resident).
// ---------------------------------------------------------------------------
__global__ __launch_bounds__(256, 2) void proj_k(const unsigned short* __restrict__ A,
                                                 const unsigned short* __restrict__ Bw,
                                                 const float* __restrict__ bias,
                                                 float* __restrict__ out) {
    const int i = blockIdx.x;
    const int n0 = ((i & 7) * 2 + ((i >> 3) & 1)) * 64;
    const int m0 = (i >> 4) * 128;
    const int tid = threadIdx.x;
    const int wave = tid >> 6, lane = tid & 63;
    const int ln = lane & 15, quad = lane >> 4;
    const int wm = (wave & 1) * 64, wn = (wave >> 1) * 32;

    __shared__ __attribute__((aligned(16))) unsigned short As[128][72];
    __shared__ __attribute__((aligned(16))) unsigned short Bs[64][72];

    // A staging: 2 threads/row, 32 cols each (4 x 8-el vectors).
    // B staging: 4 threads/row, 16 cols each (2 x 8-el vectors).
    const int arow = tid >> 1, acol = (tid & 1) * 32;
    const int brow = tid >> 2, bcol = (tid & 3) * 16;

    f32x4 acc[4][2];
#pragma unroll
    for (int mt = 0; mt < 4; mt++)
#pragma unroll
        for (int nt = 0; nt < 2; nt++) acc[mt][nt] = f32x4{0.f, 0.f, 0.f, 0.f};

    u32x4 ar0, ar1, ar2, ar3, br0, br1;
    {
        const unsigned short* ap = A + (long)(m0 + arow) * 1024 + acol;
        ar0 = *(const u32x4*)ap;        ar1 = *(const u32x4*)(ap + 8);
        ar2 = *(const u32x4*)(ap + 16); ar3 = *(const u32x4*)(ap + 24);
        const unsigned short* bp = Bw + (long)(n0 + brow) * 1024 + bcol;
        br0 = *(const u32x4*)bp; br1 = *(const u32x4*)(bp + 8);
    }

#pragma unroll 1
    for (int ks = 0; ks < 1024; ks += 64) {
        __syncthreads();
        *(u32x4*)&As[arow][acol]      = ar0;
        *(u32x4*)&As[arow][acol + 8]  = ar1;
        *(u32x4*)&As[arow][acol + 16] = ar2;
        *(u32x4*)&As[arow][acol + 24] = ar3;
        *(u32x4*)&Bs[brow][bcol]      = br0;
        *(u32x4*)&Bs[brow][bcol + 8]  = br1;
        __syncthreads();

        if (ks + 64 < 1024) {
            const unsigned short* ap = A + (long)(m0 + arow) * 1024 + ks + 64 + acol;
            ar0 = *(const u32x4*)ap;        ar1 = *(const u32x4*)(ap + 8);
            ar2 = *(const u32x4*)(ap + 16); ar3 = *(const u32x4*)(ap + 24);
            const unsigned short* bp = Bw + (long)(n0 + brow) * 1024 + ks + 64 + bcol;
            br0 = *(const u32x4*)bp; br1 = *(const u32x4*)(bp + 8);
        }

        bf16x8 bf[2][2];
#pragma unroll
        for (int nt = 0; nt < 2; nt++) {
            bf[nt][0] = *(const bf16x8*)&Bs[wn + nt * 16 + ln][quad * 8];
            bf[nt][1] = *(const bf16x8*)&Bs[wn + nt * 16 + ln][32 + quad * 8];
        }
#pragma unroll
        for (int mt = 0; mt < 4; mt++) {
            bf16x8 af0 = *(const bf16x8*)&As[wm + mt * 16 + ln][quad * 8];
            bf16x8 af1 = *(const bf16x8*)&As[wm + mt * 16 + ln][32 + quad * 8];
#pragma unroll
            for (int nt = 0; nt < 2; nt++) {
                acc[mt][nt] = __builtin_amdgcn_mfma_f32_16x16x32_bf16(af0, bf[nt][0], acc[mt][nt], 0, 0, 0);
                acc[mt][nt] = __builtin_amdgcn_mfma_f32_16x16x32_bf16(af1, bf[nt][1], acc[mt][nt], 0, 0, 0);
            }
        }
    }

#pragma unroll
    for (int nt = 0; nt < 2; nt++) {
        int col = n0 + wn + nt * 16 + ln;
        float bz = bias[col];
#pragma unroll
        for (int mt = 0; mt < 4; mt++)
#pragma unroll
            for (int r = 0; r < 4; r++) {
                int row = m0 + wm + mt * 16 + quad * 4 + r;
                out[(long)row * 1024 + col] = acc[mt][nt][r] + bz;
            }
    }
}

extern "C" void kernel_launch(void* const* d_in, const int* in_sizes, int n_in,
                              void* d_out, int out_size, void* d_ws, size_t ws_size,
                              hipStream_t stream) {
    const float* q    = (const float*)d_in[0];
    const float* k    = (const float*)d_in[1];
    const float* v    = (const float*)d_in[2];
    const float* Wo_w = (const float*)d_in[3];
    const float* Wo_b = (const float*)d_in[4];
    float* out = (float*)d_out;

    unsigned short* ctx = (unsigned short*)d_ws;           // [4096][1024]   8.4 MB
    unsigned short* wob = ctx + (size_t)4096 * 1024;       // [1024][1024]   2.1 MB
    unsigned short* kbb = wob + (size_t)1024 * 1024;       // [32][2048][64] 8.4 MB
    unsigned short* vtb = kbb + (size_t)32 * 2048 * 64;    // [32][64][2048] 8.4 MB
    float* Opart = (float*)(vtb + (size_t)32 * 2048 * 64); // [2][32][16][64][128] 33.6 MB
    float* lpart = Opart + (size_t)2 * 32 * 16 * 64 * 128; // [2][32][16][128] 512 KB
    int*   flags = (int*)(lpart + (size_t)2 * 32 * 16 * 128); // flags[512]

    prep_k<<<3073, 256, 0, stream>>>(k, v, Wo_w, kbb, vtb, wob, flags);
    attn_k<<<1024, 256, 0, stream>>>(q, kbb, vtb, ctx, Opart, lpart, flags);
    proj_k<<<512, 256, 0, stream>>>(ctx, wob, Wo_b, out);
}